// Round 2
// baseline (2380.644 us; speedup 1.0000x reference)
//
#include <hip/hip_runtime.h>

// GCN: 2x GCNConv(+self-loop sym-norm) + ReLU, global mean pool, linear head.
// N=100000, E=1600000, G=100, D_IN=3, H=128, OUT=10.
//
// All kernels static + uniquely prefixed: the harness loads many solution
// .so's in one process; generic __global__ names collide across libraries and
// launches silently bind to the wrong device function (round-1 failure mode).
//
// Runtime dtype probe: harness may feed float arrays as bf16 or fp32. We
// detect once (exponent-field statistics of x reinterpreted as ushorts),
// convert everything to fp32 scratch, and write d_out in the detected dtype.
//
// Algebraic move: layer-1 aggregates x (3 feats) BEFORE the W1 matmul
// (linearity of GCN aggregation) -> 42x fewer scatter-adds than aggregating
// in H=128 space.

#define DIN 3
#define H 128
#define OUTF 10
#define NWEIGHT (384 + 128 + 16384 + 128 + 1280 + 10)  // W1,b1,W2,b2,Wl,bl

__device__ __forceinline__ float gcn364_bf2f(unsigned short u) {
    return __uint_as_float(((unsigned int)u) << 16);
}
__device__ __forceinline__ unsigned short gcn364_f2bf(float f) {
    unsigned int u = __float_as_uint(f);
    u += 0x7FFFu + ((u >> 16) & 1u);   // round-to-nearest-even
    return (unsigned short)(u >> 16);
}

// ---- dtype probe: flag=1 if x is fp32, flag=0 if bf16 ----
static __global__ void gcn364_detect(const unsigned short* __restrict__ xraw,
                                     int* __restrict__ flag) {
    __shared__ int cnt;
    if (threadIdx.x == 0) cnt = 0;
    __syncthreads();
    unsigned short u = xraw[threadIdx.x];          // first 256 ushorts, in-bounds either way
    int e = (u >> 7) & 0xFF;                       // bf16 exponent field
    int outlier = (e < 100 || e > 140) ? 1 : 0;    // true bf16 N(0,1): ~0 outliers
    atomicAdd(&cnt, outlier);
    __syncthreads();
    if (threadIdx.x == 0) *flag = (cnt > 32) ? 1 : 0;
}

// ---- convert all float inputs to one contiguous fp32 region ----
static __global__ void gcn364_convert(const void* __restrict__ x,
                                      const void* __restrict__ W1, const void* __restrict__ b1,
                                      const void* __restrict__ W2, const void* __restrict__ b2,
                                      const void* __restrict__ Wl, const void* __restrict__ bl,
                                      const int* __restrict__ flag,
                                      float* __restrict__ dst, int N) {
    int i = blockIdx.x * blockDim.x + threadIdx.x;
    int total = DIN * N + NWEIGHT;
    if (i >= total) return;
    const void* srcp; int j = i;
    if (j < DIN * N) { srcp = x; }
    else {
        j -= DIN * N;
        if      (j < 384)                       { srcp = W1; }
        else if ((j -= 384)   < 128)            { srcp = b1; }
        else if ((j -= 128)   < 16384)          { srcp = W2; }
        else if ((j -= 16384) < 128)            { srcp = b2; }
        else if ((j -= 128)   < 1280)           { srcp = Wl; }
        else    { j -= 1280;                      srcp = bl; }
    }
    float v = (*flag) ? ((const float*)srcp)[j]
                      : gcn364_bf2f(((const unsigned short*)srcp)[j]);
    dst[i] = v;
}

// deg count over dst (self-loop added later as +1)
static __global__ void gcn364_deg(const int* __restrict__ dst, float* __restrict__ degcnt, int E) {
    int e = blockIdx.x * blockDim.x + threadIdx.x;
    if (e < E) atomicAdd(&degcnt[dst[e]], 1.0f);
}

// nodes-per-graph count
static __global__ void gcn364_cnt(const int* __restrict__ batch, float* __restrict__ cnt, int N) {
    int i = blockIdx.x * blockDim.x + threadIdx.x;
    if (i < N) atomicAdd(&cnt[batch[i]], 1.0f);
}

// dinv_sqrt = rsqrt(deg+1)
static __global__ void gcn364_dinvs(const float* __restrict__ degcnt, float* __restrict__ dinvs, int N) {
    int i = blockIdx.x * blockDim.x + threadIdx.x;
    if (i < N) dinvs[i] = rsqrtf(degcnt[i] + 1.0f);
}

// layer-1 aggregation in input space (3 feats per edge)
static __global__ void gcn364_aggx(const int* __restrict__ src, const int* __restrict__ dst,
                                   const float* __restrict__ xf,
                                   const float* __restrict__ dinvs,
                                   float* __restrict__ aggX, int E) {
    int e = blockIdx.x * blockDim.x + threadIdx.x;
    if (e >= E) return;
    int s = src[e], d = dst[e];
    float nm = dinvs[s] * dinvs[d];
    atomicAdd(&aggX[d * DIN + 0], nm * xf[s * DIN + 0]);
    atomicAdd(&aggX[d * DIN + 1], nm * xf[s * DIN + 1]);
    atomicAdd(&aggX[d * DIN + 2], nm * xf[s * DIN + 2]);
}

// h1 = relu((aggX + x/deg) @ W1 + b1), stored bf16. One block (128 thr) per node.
static __global__ void gcn364_layer1(const float* __restrict__ xf,
                                     const float* __restrict__ aggX,
                                     const float* __restrict__ dinvs,
                                     const float* __restrict__ w1f,
                                     const float* __restrict__ b1f,
                                     unsigned short* __restrict__ h1, int N) {
    int i = blockIdx.x;
    int f = threadIdx.x;
    if (i >= N) return;
    float ds = dinvs[i];
    float di = ds * ds;
    float v0 = aggX[i * DIN + 0] + xf[i * DIN + 0] * di;
    float v1 = aggX[i * DIN + 1] + xf[i * DIN + 1] * di;
    float v2 = aggX[i * DIN + 2] + xf[i * DIN + 2] * di;
    float acc = v0 * w1f[0 * H + f] + v1 * w1f[1 * H + f] + v2 * w1f[2 * H + f] + b1f[f];
    h1[(size_t)i * H + f] = gcn364_f2bf(fmaxf(acc, 0.0f));
}

// layer-2 edge aggregation: one wave per edge, lane handles feature pair.
static __global__ void gcn364_agg2(const int* __restrict__ src, const int* __restrict__ dst,
                                   const unsigned short* __restrict__ h1,
                                   const float* __restrict__ dinvs,
                                   float* __restrict__ a2, int E) {
    int e = blockIdx.x * 4 + (threadIdx.x >> 6);
    int lane = threadIdx.x & 63;
    if (e >= E) return;
    int s = src[e], d = dst[e];
    float nm = dinvs[s] * dinvs[d];
    unsigned int hv = *(const unsigned int*)(h1 + (size_t)s * H + 2 * lane);
    float lo = gcn364_bf2f((unsigned short)(hv & 0xffffu));
    float hi = gcn364_bf2f((unsigned short)(hv >> 16));
    float* ap = a2 + (size_t)d * H + 2 * lane;
    atomicAdd(ap + 0, nm * lo);
    atomicAdd(ap + 1, nm * hi);
}

// layer 2 matmul + relu + fused mean-pool accumulation.
// Block: 256 threads = (f in [0,128)) x (half in {0,1}); 8 nodes per block.
#define MPB 8
static __global__ void gcn364_layer2pool(const float* __restrict__ a2,
                                         const unsigned short* __restrict__ h1,
                                         const float* __restrict__ dinvs,
                                         const float* __restrict__ w2f,
                                         const float* __restrict__ b2f,
                                         const int* __restrict__ batch,
                                         float* __restrict__ pooled, int N) {
    __shared__ float vsh[MPB][H];
    int i0 = blockIdx.x * MPB;
    int f = threadIdx.x & (H - 1);
    int half = threadIdx.x >> 7;

    for (int t = 0; t < 4; t++) {
        int idx = threadIdx.x + t * 256;
        int node = idx >> 7;
        int ff = idx & (H - 1);
        int i = i0 + node;
        float v = 0.0f;
        if (i < N) {
            float ds = dinvs[i];
            v = a2[(size_t)i * H + ff] + gcn364_bf2f(h1[(size_t)i * H + ff]) * ds * ds;
        }
        vsh[node][ff] = v;
    }
    __syncthreads();

    float acc[4] = {0.f, 0.f, 0.f, 0.f};
    for (int k = 0; k < H; k++) {
        float w = w2f[k * H + f];
        acc[0] += vsh[half + 0][k] * w;
        acc[1] += vsh[half + 2][k] * w;
        acc[2] += vsh[half + 4][k] * w;
        acc[3] += vsh[half + 6][k] * w;
    }
    float bb = b2f[f];

    // batch is sorted -> group consecutive same-graph nodes before atomics
    float sum = 0.0f;
    int curg = -1;
    for (int j = 0; j < 4; j++) {
        int i = i0 + half + 2 * j;
        if (i >= N) continue;
        float val = fmaxf(acc[j] + bb, 0.0f);
        int g = batch[i];
        if (g != curg) {
            if (curg >= 0) atomicAdd(&pooled[curg * H + f], sum);
            curg = g;
            sum = 0.0f;
        }
        sum += val;
    }
    if (curg >= 0) atomicAdd(&pooled[curg * H + f], sum);
}

// out[g] = (pooled[g]/max(cnt,1)) @ Wl + bl  -> detected dtype
static __global__ void gcn364_final(const float* __restrict__ pooled,
                                    const float* __restrict__ cnt,
                                    const float* __restrict__ wlf,
                                    const float* __restrict__ blf,
                                    const int* __restrict__ flag,
                                    void* __restrict__ out, int G) {
    int g = blockIdx.x;
    int o = threadIdx.x;
    if (g >= G || o >= OUTF) return;
    float inv = 1.0f / fmaxf(cnt[g], 1.0f);
    float acc = 0.0f;
    for (int k = 0; k < H; k++)
        acc += pooled[g * H + k] * wlf[k * OUTF + o];
    float v = acc * inv + blf[o];
    if (*flag) ((float*)out)[g * OUTF + o] = v;
    else       ((unsigned short*)out)[g * OUTF + o] = gcn364_f2bf(v);
}

extern "C" void kernel_launch(void* const* d_in, const int* in_sizes, int n_in,
                              void* d_out, int out_size, void* d_ws, size_t ws_size,
                              hipStream_t stream) {
    const void* x  = d_in[0];
    const int* edge_index = (const int*)d_in[1];
    const int* batch      = (const int*)d_in[2];
    const void* W1 = d_in[3];
    const void* b1 = d_in[4];
    const void* W2 = d_in[5];
    const void* b2 = d_in[6];
    const void* Wl = d_in[7];
    const void* bl = d_in[8];

    const int N = in_sizes[0] / DIN;
    const int E = in_sizes[1] / 2;
    const int G = out_size / OUTF;
    const int* src = edge_index;
    const int* dst = edge_index + E;

    // ---- workspace layout (floats) ----
    float* ws = (float*)d_ws;
    float* degcnt = ws;                               // N    (zeroed)
    float* cnt    = degcnt + N;                       // G    (zeroed)
    float* pooled = cnt + G;                          // G*H  (zeroed)
    float* aggX   = pooled + (size_t)G * H;           // 3N   (zeroed)
    float* a2     = aggX + (size_t)DIN * N;           // N*H  (zeroed)
    float* dinvs  = a2 + (size_t)N * H;               // N
    float* xf     = dinvs + N;                        // 3N   (converted x)
    float* wf     = xf + (size_t)DIN * N;             // NWEIGHT (converted weights)
    int*   flag   = (int*)(wf + NWEIGHT);             // 1
    unsigned short* h1 = (unsigned short*)(flag + 1); // N*H ushorts

    float* w1f = wf;
    float* b1f = w1f + 384;
    float* w2f = b1f + 128;
    float* b2f = w2f + 16384;
    float* wlf = b2f + 128;
    float* blf = wlf + 1280;

    size_t zero_bytes = ((size_t)N + G + (size_t)G * H + (size_t)DIN * N + (size_t)N * H) * 4;
    hipMemsetAsync(d_ws, 0, zero_bytes, stream);

    gcn364_detect<<<1, 256, 0, stream>>>((const unsigned short*)x, flag);
    {
        int total = DIN * N + NWEIGHT;
        gcn364_convert<<<(total + 255) / 256, 256, 0, stream>>>(
            x, W1, b1, W2, b2, Wl, bl, flag, xf, N);
    }
    gcn364_deg<<<(E + 255) / 256, 256, 0, stream>>>(dst, degcnt, E);
    gcn364_cnt<<<(N + 255) / 256, 256, 0, stream>>>(batch, cnt, N);
    gcn364_dinvs<<<(N + 255) / 256, 256, 0, stream>>>(degcnt, dinvs, N);
    gcn364_aggx<<<(E + 255) / 256, 256, 0, stream>>>(src, dst, xf, dinvs, aggX, E);
    gcn364_layer1<<<N, H, 0, stream>>>(xf, aggX, dinvs, w1f, b1f, h1, N);
    gcn364_agg2<<<(E + 3) / 4, 256, 0, stream>>>(src, dst, h1, dinvs, a2, E);
    gcn364_layer2pool<<<(N + MPB - 1) / MPB, 256, 0, stream>>>(
        a2, h1, dinvs, w2f, b2f, batch, pooled, N);
    gcn364_final<<<G, 64, 0, stream>>>(pooled, cnt, wlf, blf, flag, d_out, G);
}

// Round 3
// 582.100 us; speedup vs baseline: 4.0897x; 4.0897x over previous
//
#include <hip/hip_runtime.h>

// GCN: 2x GCNConv(+self-loop sym-norm) + ReLU, global mean pool, linear head.
// N=100000, E=1600000, G=100, D_IN=3, H=128, OUT=10.
//
// Round-3 structure: build dst-CSR (deg -> scan -> fill), then all
// aggregations are segmented reductions with ZERO float atomics.
// Round-2 counters: agg2 atomics caused WRITE_SIZE=1.7GB, 1447us.
//
// All kernels static + gcn364_ prefix (symbol collisions across loaded .so's
// caused the round-1 silent failure). Runtime dtype probe handles bf16/fp32.

#define DIN 3
#define H 128
#define OUTF 10
#define NWEIGHT (384 + 128 + 16384 + 128 + 1280 + 10)  // W1,b1,W2,b2,Wl,bl

__device__ __forceinline__ float gcn364_bf2f(unsigned short u) {
    return __uint_as_float(((unsigned int)u) << 16);
}
__device__ __forceinline__ unsigned short gcn364_f2bf(float f) {
    unsigned int u = __float_as_uint(f);
    u += 0x7FFFu + ((u >> 16) & 1u);   // round-to-nearest-even
    return (unsigned short)(u >> 16);
}

// ---- dtype probe: flag=1 if x is fp32, flag=0 if bf16 ----
static __global__ void gcn364_detect(const unsigned short* __restrict__ xraw,
                                     int* __restrict__ flag) {
    __shared__ int cnt;
    if (threadIdx.x == 0) cnt = 0;
    __syncthreads();
    unsigned short u = xraw[threadIdx.x];
    int e = (u >> 7) & 0xFF;                       // bf16 exponent field
    int outlier = (e < 100 || e > 140) ? 1 : 0;    // true bf16 N(0,1): ~0 outliers
    atomicAdd(&cnt, outlier);
    __syncthreads();
    if (threadIdx.x == 0) *flag = (cnt > 32) ? 1 : 0;
}

// ---- convert all float inputs to one contiguous fp32 region ----
static __global__ void gcn364_convert(const void* __restrict__ x,
                                      const void* __restrict__ W1, const void* __restrict__ b1,
                                      const void* __restrict__ W2, const void* __restrict__ b2,
                                      const void* __restrict__ Wl, const void* __restrict__ bl,
                                      const int* __restrict__ flag,
                                      float* __restrict__ dst, int N) {
    int i = blockIdx.x * blockDim.x + threadIdx.x;
    int total = DIN * N + NWEIGHT;
    if (i >= total) return;
    const void* srcp; int j = i;
    if (j < DIN * N) { srcp = x; }
    else {
        j -= DIN * N;
        if      (j < 384)                       { srcp = W1; }
        else if ((j -= 384)   < 128)            { srcp = b1; }
        else if ((j -= 128)   < 16384)          { srcp = W2; }
        else if ((j -= 16384) < 128)            { srcp = b2; }
        else if ((j -= 128)   < 1280)           { srcp = Wl; }
        else    { j -= 1280;                      srcp = bl; }
    }
    float v = (*flag) ? ((const float*)srcp)[j]
                      : gcn364_bf2f(((const unsigned short*)srcp)[j]);
    dst[i] = v;
}

// int degree count over dst
static __global__ void gcn364_deg(const int* __restrict__ dst, int* __restrict__ deg, int E) {
    int e = blockIdx.x * blockDim.x + threadIdx.x;
    if (e < E) atomicAdd(&deg[dst[e]], 1);
}

// nodes-per-graph via binary search on sorted batch (no atomics)
static __global__ void gcn364_cnt(const int* __restrict__ batch, float* __restrict__ cnt,
                                  int N, int G) {
    int g = blockIdx.x * blockDim.x + threadIdx.x;
    if (g >= G) return;
    // lower_bound(g) and lower_bound(g+1)
    int lo = 0, hi = N;
    while (lo < hi) { int m = (lo + hi) >> 1; if (batch[m] < g) lo = m + 1; else hi = m; }
    int a = lo;
    lo = 0; hi = N;
    while (lo < hi) { int m = (lo + hi) >> 1; if (batch[m] < g + 1) lo = m + 1; else hi = m; }
    cnt[g] = (float)(lo - a);
}

static __global__ void gcn364_dinvs(const int* __restrict__ deg, float* __restrict__ dinvs, int N) {
    int i = blockIdx.x * blockDim.x + threadIdx.x;
    if (i < N) dinvs[i] = rsqrtf((float)deg[i] + 1.0f);
}

// ---- exclusive scan of deg[N] -> off[N], 1024 items/block ----
static __global__ void gcn364_scan1(const int* __restrict__ deg, int* __restrict__ off,
                                    int* __restrict__ partials, int N) {
    __shared__ int sh[256];
    int t = threadIdx.x;
    int base = blockIdx.x * 1024 + t * 4;
    int v0 = (base + 0 < N) ? deg[base + 0] : 0;
    int v1 = (base + 1 < N) ? deg[base + 1] : 0;
    int v2 = (base + 2 < N) ? deg[base + 2] : 0;
    int v3 = (base + 3 < N) ? deg[base + 3] : 0;
    int s = v0 + v1 + v2 + v3;
    sh[t] = s;
    __syncthreads();
    for (int d = 1; d < 256; d <<= 1) {
        int val = (t >= d) ? sh[t - d] : 0;
        __syncthreads();
        sh[t] += val;
        __syncthreads();
    }
    int excl = sh[t] - s;
    int run = excl;
    if (base + 0 < N) off[base + 0] = run; run += v0;
    if (base + 1 < N) off[base + 1] = run; run += v1;
    if (base + 2 < N) off[base + 2] = run; run += v2;
    if (base + 3 < N) off[base + 3] = run;
    if (t == 255) partials[blockIdx.x] = sh[255];
}

static __global__ void gcn364_scan2(int* __restrict__ partials, int nb) {
    __shared__ int sh[256];
    int t = threadIdx.x;
    int v = (t < nb) ? partials[t] : 0;
    sh[t] = v;
    __syncthreads();
    for (int d = 1; d < 256; d <<= 1) {
        int val = (t >= d) ? sh[t - d] : 0;
        __syncthreads();
        sh[t] += val;
        __syncthreads();
    }
    if (t < nb) partials[t] = sh[t] - v;   // exclusive
}

static __global__ void gcn364_scan3(int* __restrict__ off, const int* __restrict__ partials, int N) {
    int i = blockIdx.x * blockDim.x + threadIdx.x;
    if (i < N) off[i] += partials[i >> 10];
}

// bucket fill: off[] doubles as cursor; afterwards off[i] == end offset of node i
static __global__ void gcn364_fill(const int* __restrict__ src, const int* __restrict__ dst,
                                   int* __restrict__ off, int* __restrict__ esrc, int E) {
    int e = blockIdx.x * blockDim.x + threadIdx.x;
    if (e >= E) return;
    int p = atomicAdd(&off[dst[e]], 1);
    esrc[p] = src[e];
}

// layer-1 aggregation in input space via CSR: one thread per node, no atomics
static __global__ void gcn364_agg1(const int* __restrict__ esrc, const int* __restrict__ endoff,
                                   const float* __restrict__ xf, const float* __restrict__ dinvs,
                                   float* __restrict__ aggX, int N) {
    int i = blockIdx.x * blockDim.x + threadIdx.x;
    if (i >= N) return;
    int p0 = (i == 0) ? 0 : endoff[i - 1];
    int p1 = endoff[i];
    float di = dinvs[i];
    float a0 = 0.f, a1 = 0.f, a2 = 0.f;
    for (int p = p0; p < p1; p++) {
        int s = esrc[p];
        float nm = di * dinvs[s];
        a0 += nm * xf[s * DIN + 0];
        a1 += nm * xf[s * DIN + 1];
        a2 += nm * xf[s * DIN + 2];
    }
    aggX[i * DIN + 0] = a0;
    aggX[i * DIN + 1] = a1;
    aggX[i * DIN + 2] = a2;
}

// h1 = relu((aggX + x/deg) @ W1 + b1), bf16. One thread per (node,feat).
static __global__ void gcn364_layer1(const float* __restrict__ xf,
                                     const float* __restrict__ aggX,
                                     const float* __restrict__ dinvs,
                                     const float* __restrict__ w1f,
                                     const float* __restrict__ b1f,
                                     unsigned short* __restrict__ h1, int N) {
    int gid = blockIdx.x * blockDim.x + threadIdx.x;
    int i = gid >> 7;
    int f = gid & (H - 1);
    if (i >= N) return;
    float ds = dinvs[i];
    float di = ds * ds;
    float v0 = aggX[i * DIN + 0] + xf[i * DIN + 0] * di;
    float v1 = aggX[i * DIN + 1] + xf[i * DIN + 1] * di;
    float v2 = aggX[i * DIN + 2] + xf[i * DIN + 2] * di;
    float acc = v0 * w1f[0 * H + f] + v1 * w1f[1 * H + f] + v2 * w1f[2 * H + f] + b1f[f];
    h1[(size_t)i * H + f] = gcn364_f2bf(fmaxf(acc, 0.0f));
}

// layer-2 aggregation via CSR: one wave per node, lane = feature pair.
// v = sum_edges nm*h1[src] + h1[i]/deg  -> packed bf16 write (one uint/lane)
static __global__ void gcn364_agg2(const int* __restrict__ esrc, const int* __restrict__ endoff,
                                   const unsigned short* __restrict__ h1,
                                   const float* __restrict__ dinvs,
                                   unsigned int* __restrict__ v2, int N) {
    int i = blockIdx.x * 4 + (threadIdx.x >> 6);
    int lane = threadIdx.x & 63;
    if (i >= N) return;
    int p0 = (i == 0) ? 0 : endoff[i - 1];
    int p1 = endoff[i];
    float di = dinvs[i];
    float a0 = 0.f, a1 = 0.f;
    const unsigned int* h1u = (const unsigned int*)h1;
    for (int p = p0; p < p1; p++) {
        int s = esrc[p];
        float nm = di * dinvs[s];
        unsigned int hv = h1u[(size_t)s * (H / 2) + lane];
        a0 += nm * gcn364_bf2f((unsigned short)(hv & 0xffffu));
        a1 += nm * gcn364_bf2f((unsigned short)(hv >> 16));
    }
    {   // self-loop
        unsigned int hv = h1u[(size_t)i * (H / 2) + lane];
        float d2 = di * di;
        a0 += d2 * gcn364_bf2f((unsigned short)(hv & 0xffffu));
        a1 += d2 * gcn364_bf2f((unsigned short)(hv >> 16));
    }
    v2[(size_t)i * (H / 2) + lane] =
        (unsigned int)gcn364_f2bf(a0) | ((unsigned int)gcn364_f2bf(a1) << 16);
}

// layer 2 matmul + relu + fused mean-pool accumulation.
#define MPB 8
static __global__ void gcn364_layer2pool(const unsigned int* __restrict__ v2,
                                         const float* __restrict__ w2f,
                                         const float* __restrict__ b2f,
                                         const int* __restrict__ batch,
                                         float* __restrict__ pooled, int N) {
    __shared__ float vsh[MPB][H];
    int i0 = blockIdx.x * MPB;
    int f = threadIdx.x & (H - 1);
    int half = threadIdx.x >> 7;

    // stage v for 8 nodes: 512 uints by 256 threads (2 each)
    for (int t = 0; t < 2; t++) {
        int idx = threadIdx.x + t * 256;         // uint index within tile
        int node = idx >> 6;
        int ff = idx & 63;
        int i = i0 + node;
        unsigned int hv = (i < N) ? v2[(size_t)i * (H / 2) + ff] : 0u;
        vsh[node][2 * ff + 0] = gcn364_bf2f((unsigned short)(hv & 0xffffu));
        vsh[node][2 * ff + 1] = gcn364_bf2f((unsigned short)(hv >> 16));
    }
    __syncthreads();

    float acc[4] = {0.f, 0.f, 0.f, 0.f};
    for (int k = 0; k < H; k++) {
        float w = w2f[k * H + f];
        acc[0] += vsh[half + 0][k] * w;
        acc[1] += vsh[half + 2][k] * w;
        acc[2] += vsh[half + 4][k] * w;
        acc[3] += vsh[half + 6][k] * w;
    }
    float bb = b2f[f];

    // batch sorted -> group consecutive same-graph nodes before atomics
    float sum = 0.0f;
    int curg = -1;
    for (int j = 0; j < 4; j++) {
        int i = i0 + half + 2 * j;
        if (i >= N) continue;
        float val = fmaxf(acc[j] + bb, 0.0f);
        int g = batch[i];
        if (g != curg) {
            if (curg >= 0) atomicAdd(&pooled[curg * H + f], sum);
            curg = g;
            sum = 0.0f;
        }
        sum += val;
    }
    if (curg >= 0) atomicAdd(&pooled[curg * H + f], sum);
}

// out[g] = (pooled[g]/max(cnt,1)) @ Wl + bl  -> detected dtype
static __global__ void gcn364_final(const float* __restrict__ pooled,
                                    const float* __restrict__ cnt,
                                    const float* __restrict__ wlf,
                                    const float* __restrict__ blf,
                                    const int* __restrict__ flag,
                                    void* __restrict__ out, int G) {
    int g = blockIdx.x;
    int o = threadIdx.x;
    if (g >= G || o >= OUTF) return;
    float inv = 1.0f / fmaxf(cnt[g], 1.0f);
    float acc = 0.0f;
    for (int k = 0; k < H; k++)
        acc += pooled[g * H + k] * wlf[k * OUTF + o];
    float v = acc * inv + blf[o];
    if (*flag) ((float*)out)[g * OUTF + o] = v;
    else       ((unsigned short*)out)[g * OUTF + o] = gcn364_f2bf(v);
}

extern "C" void kernel_launch(void* const* d_in, const int* in_sizes, int n_in,
                              void* d_out, int out_size, void* d_ws, size_t ws_size,
                              hipStream_t stream) {
    const void* x  = d_in[0];
    const int* edge_index = (const int*)d_in[1];
    const int* batch      = (const int*)d_in[2];
    const void* W1 = d_in[3];
    const void* b1 = d_in[4];
    const void* W2 = d_in[5];
    const void* b2 = d_in[6];
    const void* Wl = d_in[7];
    const void* bl = d_in[8];

    const int N = in_sizes[0] / DIN;
    const int E = in_sizes[1] / 2;
    const int G = out_size / OUTF;
    const int* src = edge_index;
    const int* dst = edge_index + E;
    const int NB = (N + 1023) / 1024;   // scan blocks (must be <= 256)

    // ---- workspace layout (4B units) ----
    char* wsb = (char*)d_ws;
    int*   deg      = (int*)wsb;                                  // N      (zeroed)
    float* pooled   = (float*)(deg + N);                          // G*H    (zeroed)
    int*   off      = (int*)(pooled + (size_t)G * H);             // N
    int*   partials = off + N;                                    // 256
    float* cnt      = (float*)(partials + 256);                   // G
    float* aggX     = cnt + G;                                    // 3N
    unsigned int* v2 = (unsigned int*)(aggX + (size_t)DIN * N);   // N*H/2 uints (bf16 pairs)
    float* dinvs    = (float*)(v2 + (size_t)N * (H / 2));         // N
    float* xf       = dinvs + N;                                  // 3N
    float* wf       = xf + (size_t)DIN * N;                       // NWEIGHT
    int*   flag     = (int*)(wf + NWEIGHT);                       // 1
    int*   esrc     = flag + 1;                                   // E
    unsigned short* h1 = (unsigned short*)(esrc + E);             // N*H ushorts

    float* w1f = wf;
    float* b1f = w1f + 384;
    float* w2f = b1f + 128;
    float* b2f = w2f + 16384;
    float* wlf = b2f + 128;
    float* blf = wlf + 1280;

    // zero only deg + pooled (contiguous at ws start)
    hipMemsetAsync(d_ws, 0, ((size_t)N + (size_t)G * H) * 4, stream);

    gcn364_detect<<<1, 256, 0, stream>>>((const unsigned short*)x, flag);
    {
        int total = DIN * N + NWEIGHT;
        gcn364_convert<<<(total + 255) / 256, 256, 0, stream>>>(
            x, W1, b1, W2, b2, Wl, bl, flag, xf, N);
    }
    gcn364_deg<<<(E + 255) / 256, 256, 0, stream>>>(dst, deg, E);
    gcn364_cnt<<<(G + 63) / 64, 64, 0, stream>>>(batch, cnt, N, G);
    gcn364_dinvs<<<(N + 255) / 256, 256, 0, stream>>>(deg, dinvs, N);
    gcn364_scan1<<<NB, 256, 0, stream>>>(deg, off, partials, N);
    gcn364_scan2<<<1, 256, 0, stream>>>(partials, NB);
    gcn364_scan3<<<(N + 255) / 256, 256, 0, stream>>>(off, partials, N);
    gcn364_fill<<<(E + 255) / 256, 256, 0, stream>>>(src, dst, off, esrc, E);
    gcn364_agg1<<<(N + 255) / 256, 256, 0, stream>>>(esrc, off, xf, dinvs, aggX, N);
    gcn364_layer1<<<((size_t)N * H + 255) / 256, 256, 0, stream>>>(
        xf, aggX, dinvs, w1f, b1f, h1, N);
    gcn364_agg2<<<(N + 3) / 4, 256, 0, stream>>>(esrc, off, h1, dinvs, v2, N);
    gcn364_layer2pool<<<(N + MPB - 1) / MPB, 256, 0, stream>>>(
        v2, w2f, b2f, batch, pooled, N);
    gcn364_final<<<G, 64, 0, stream>>>(pooled, cnt, wlf, blf, flag, d_out, G);
}

// Round 4
// 510.574 us; speedup vs baseline: 4.6627x; 1.1401x over previous
//
#include <hip/hip_runtime.h>

// GCN: 2x GCNConv(+self-loop sym-norm) + ReLU, global mean pool, linear head.
// N=100000, E=1600000, G=100, D_IN=3, H=128, OUT=10.
//
// R3->R4: (1) pre-scale features by dinvs at producer (kills per-edge dinvs
// gather), (2) fuse agg2+layer2pool (kills 38MB v2 round-trip, overlaps
// gather stalls with GEMM work), (3) shfl-broadcast CSR gather (coalesced
// esrc, scalar index -> coalesced 256B row loads), (4) float4 LDS reads in
// GEMM (4x fewer ds instrs).
//
// All kernels static + gcn364_ prefix (cross-.so symbol collisions caused the
// round-1 silent failure). Runtime dtype probe handles bf16/fp32 harness mode.

#define DIN 3
#define H 128
#define OUTF 10
#define NWEIGHT (384 + 128 + 16384 + 128 + 1280 + 10)  // W1,b1,W2,b2,Wl,bl

__device__ __forceinline__ float gcn364_bf2f(unsigned short u) {
    return __uint_as_float(((unsigned int)u) << 16);
}
__device__ __forceinline__ unsigned short gcn364_f2bf(float f) {
    unsigned int u = __float_as_uint(f);
    u += 0x7FFFu + ((u >> 16) & 1u);   // round-to-nearest-even
    return (unsigned short)(u >> 16);
}

// ---- dtype probe: flag=1 if x is fp32, flag=0 if bf16 ----
static __global__ void gcn364_detect(const unsigned short* __restrict__ xraw,
                                     int* __restrict__ flag) {
    __shared__ int cnt;
    if (threadIdx.x == 0) cnt = 0;
    __syncthreads();
    unsigned short u = xraw[threadIdx.x];
    int e = (u >> 7) & 0xFF;
    int outlier = (e < 100 || e > 140) ? 1 : 0;
    atomicAdd(&cnt, outlier);
    __syncthreads();
    if (threadIdx.x == 0) *flag = (cnt > 32) ? 1 : 0;
}

// ---- convert all float inputs to one contiguous fp32 region ----
static __global__ void gcn364_convert(const void* __restrict__ x,
                                      const void* __restrict__ W1, const void* __restrict__ b1,
                                      const void* __restrict__ W2, const void* __restrict__ b2,
                                      const void* __restrict__ Wl, const void* __restrict__ bl,
                                      const int* __restrict__ flag,
                                      float* __restrict__ dst, int N) {
    int i = blockIdx.x * blockDim.x + threadIdx.x;
    int total = DIN * N + NWEIGHT;
    if (i >= total) return;
    const void* srcp; int j = i;
    if (j < DIN * N) { srcp = x; }
    else {
        j -= DIN * N;
        if      (j < 384)                       { srcp = W1; }
        else if ((j -= 384)   < 128)            { srcp = b1; }
        else if ((j -= 128)   < 16384)          { srcp = W2; }
        else if ((j -= 16384) < 128)            { srcp = b2; }
        else if ((j -= 128)   < 1280)           { srcp = Wl; }
        else    { j -= 1280;                      srcp = bl; }
    }
    float v = (*flag) ? ((const float*)srcp)[j]
                      : gcn364_bf2f(((const unsigned short*)srcp)[j]);
    dst[i] = v;
}

// int degree count over dst
static __global__ void gcn364_deg(const int* __restrict__ dst, int* __restrict__ deg, int E) {
    int e = blockIdx.x * blockDim.x + threadIdx.x;
    if (e < E) atomicAdd(&deg[dst[e]], 1);
}

// nodes-per-graph via binary search on sorted batch (no atomics)
static __global__ void gcn364_cnt(const int* __restrict__ batch, float* __restrict__ cnt,
                                  int N, int G) {
    int g = blockIdx.x * blockDim.x + threadIdx.x;
    if (g >= G) return;
    int lo = 0, hi = N;
    while (lo < hi) { int m = (lo + hi) >> 1; if (batch[m] < g) lo = m + 1; else hi = m; }
    int a = lo;
    lo = 0; hi = N;
    while (lo < hi) { int m = (lo + hi) >> 1; if (batch[m] < g + 1) lo = m + 1; else hi = m; }
    cnt[g] = (float)(lo - a);
}

// ---- exclusive scan of deg[N] -> off[N], 1024 items/block ----
static __global__ void gcn364_scan1(const int* __restrict__ deg, int* __restrict__ off,
                                    int* __restrict__ partials, int N) {
    __shared__ int sh[256];
    int t = threadIdx.x;
    int base = blockIdx.x * 1024 + t * 4;
    int v0 = (base + 0 < N) ? deg[base + 0] : 0;
    int v1 = (base + 1 < N) ? deg[base + 1] : 0;
    int v2 = (base + 2 < N) ? deg[base + 2] : 0;
    int v3 = (base + 3 < N) ? deg[base + 3] : 0;
    int s = v0 + v1 + v2 + v3;
    sh[t] = s;
    __syncthreads();
    for (int d = 1; d < 256; d <<= 1) {
        int val = (t >= d) ? sh[t - d] : 0;
        __syncthreads();
        sh[t] += val;
        __syncthreads();
    }
    int excl = sh[t] - s;
    int run = excl;
    if (base + 0 < N) off[base + 0] = run; run += v0;
    if (base + 1 < N) off[base + 1] = run; run += v1;
    if (base + 2 < N) off[base + 2] = run; run += v2;
    if (base + 3 < N) off[base + 3] = run;
    if (t == 255) partials[blockIdx.x] = sh[255];
}

static __global__ void gcn364_scan2(int* __restrict__ partials, int nb) {
    __shared__ int sh[256];
    int t = threadIdx.x;
    int v = (t < nb) ? partials[t] : 0;
    sh[t] = v;
    __syncthreads();
    for (int d = 1; d < 256; d <<= 1) {
        int val = (t >= d) ? sh[t - d] : 0;
        __syncthreads();
        sh[t] += val;
        __syncthreads();
    }
    if (t < nb) partials[t] = sh[t] - v;   // exclusive
}

// scan finalize + dinvs + in-place pre-scale of xf by dinvs
static __global__ void gcn364_scan3(int* __restrict__ off, const int* __restrict__ partials,
                                    const int* __restrict__ deg, float* __restrict__ dinvs,
                                    float* __restrict__ xf, int N) {
    int i = blockIdx.x * blockDim.x + threadIdx.x;
    if (i >= N) return;
    off[i] += partials[i >> 10];
    float di = rsqrtf((float)deg[i] + 1.0f);
    dinvs[i] = di;
    xf[i * DIN + 0] *= di;
    xf[i * DIN + 1] *= di;
    xf[i * DIN + 2] *= di;
}

// bucket fill: off[] doubles as cursor; afterwards off[i] == end offset of node i
static __global__ void gcn364_fill(const int* __restrict__ src, const int* __restrict__ dst,
                                   int* __restrict__ off, int* __restrict__ esrc, int E) {
    int e = blockIdx.x * blockDim.x + threadIdx.x;
    if (e >= E) return;
    int p = atomicAdd(&off[dst[e]], 1);
    esrc[p] = src[e];
}

// layer-1 aggregation in input space via CSR (xf pre-scaled by dinvs[src]):
// aggX[i] = dinvs[i] * sum_edges xf[s]
static __global__ void gcn364_agg1(const int* __restrict__ esrc, const int* __restrict__ endoff,
                                   const float* __restrict__ xf, const float* __restrict__ dinvs,
                                   float* __restrict__ aggX, int N) {
    int i = blockIdx.x * blockDim.x + threadIdx.x;
    if (i >= N) return;
    int p0 = (i == 0) ? 0 : endoff[i - 1];
    int p1 = endoff[i];
    float a0 = 0.f, a1 = 0.f, a2 = 0.f;
    for (int p = p0; p < p1; p++) {
        int s = esrc[p];
        a0 += xf[s * DIN + 0];
        a1 += xf[s * DIN + 1];
        a2 += xf[s * DIN + 2];
    }
    float di = dinvs[i];
    aggX[i * DIN + 0] = di * a0;
    aggX[i * DIN + 1] = di * a1;
    aggX[i * DIN + 2] = di * a2;
}

// h1s = dinvs * relu((aggX + dinvs*xf_scaled) @ W1 + b1), bf16.
static __global__ void gcn364_layer1(const float* __restrict__ xf,
                                     const float* __restrict__ aggX,
                                     const float* __restrict__ dinvs,
                                     const float* __restrict__ w1f,
                                     const float* __restrict__ b1f,
                                     unsigned short* __restrict__ h1s, int N) {
    int gid = blockIdx.x * blockDim.x + threadIdx.x;
    int i = gid >> 7;
    int f = gid & (H - 1);
    if (i >= N) return;
    float di = dinvs[i];
    float v0 = aggX[i * DIN + 0] + xf[i * DIN + 0] * di;   // xf already has one dinvs factor
    float v1 = aggX[i * DIN + 1] + xf[i * DIN + 1] * di;
    float v2 = aggX[i * DIN + 2] + xf[i * DIN + 2] * di;
    float acc = v0 * w1f[0 * H + f] + v1 * w1f[1 * H + f] + v2 * w1f[2 * H + f] + b1f[f];
    h1s[(size_t)i * H + f] = gcn364_f2bf(di * fmaxf(acc, 0.0f));
}

// Fused: layer-2 CSR aggregation (into LDS) + GEMM + relu + mean-pool accum.
// Block = 256 thr = 4 waves; 8 nodes/block. Phase A: wave w gathers nodes
// 2w,2w+1 (lane = feature pair, shfl-broadcast src index -> coalesced 256B
// row loads, no per-edge scale since h1s is pre-scaled). Phase B: GEMM with
// float4 LDS reads, grouped atomics into pooled (batch is sorted).
#define MPB 8
static __global__ void gcn364_agg2pool(const int* __restrict__ esrc,
                                       const int* __restrict__ endoff,
                                       const unsigned int* __restrict__ h1u,
                                       const float* __restrict__ dinvs,
                                       const float* __restrict__ w2f,
                                       const float* __restrict__ b2f,
                                       const int* __restrict__ batch,
                                       float* __restrict__ pooled, int N) {
    __shared__ float vsh[MPB][H];
    int i0 = blockIdx.x * MPB;
    int wave = threadIdx.x >> 6;
    int lane = threadIdx.x & 63;

    for (int r = 0; r < 2; r++) {
        int node = wave * 2 + r;
        int i = i0 + node;
        float a0 = 0.f, a1 = 0.f;
        if (i < N) {
            int p0 = (i == 0) ? 0 : endoff[i - 1];
            int p1 = endoff[i];
            int pc = p0;
            while (pc < p1) {
                int cc = p1 - pc;
                if (cc > 64) cc = 64;
                int ev = (lane < cc) ? esrc[pc + lane] : 0;
                #pragma unroll 4
                for (int j = 0; j < cc; j++) {
                    int s = __shfl(ev, j);
                    unsigned int hv = h1u[(size_t)s * (H / 2) + lane];
                    a0 += gcn364_bf2f((unsigned short)(hv & 0xffffu));
                    a1 += gcn364_bf2f((unsigned short)(hv >> 16));
                }
                pc += cc;
            }
            unsigned int hv = h1u[(size_t)i * (H / 2) + lane];  // self-loop
            a0 += gcn364_bf2f((unsigned short)(hv & 0xffffu));
            a1 += gcn364_bf2f((unsigned short)(hv >> 16));
            float di = dinvs[i];
            a0 *= di; a1 *= di;
        }
        *(float2*)&vsh[node][2 * lane] = make_float2(a0, a1);
    }
    __syncthreads();

    int f = threadIdx.x & (H - 1);
    int half = threadIdx.x >> 7;
    float acc[4] = {0.f, 0.f, 0.f, 0.f};
    for (int k4 = 0; k4 < H / 4; k4++) {
        float4 v0 = *(const float4*)&vsh[half + 0][k4 * 4];
        float4 v1 = *(const float4*)&vsh[half + 2][k4 * 4];
        float4 v2 = *(const float4*)&vsh[half + 4][k4 * 4];
        float4 v3 = *(const float4*)&vsh[half + 6][k4 * 4];
        float w0 = w2f[(k4 * 4 + 0) * H + f];
        float w1 = w2f[(k4 * 4 + 1) * H + f];
        float w2 = w2f[(k4 * 4 + 2) * H + f];
        float w3 = w2f[(k4 * 4 + 3) * H + f];
        acc[0] += v0.x * w0 + v0.y * w1 + v0.z * w2 + v0.w * w3;
        acc[1] += v1.x * w0 + v1.y * w1 + v1.z * w2 + v1.w * w3;
        acc[2] += v2.x * w0 + v2.y * w1 + v2.z * w2 + v2.w * w3;
        acc[3] += v3.x * w0 + v3.y * w1 + v3.z * w2 + v3.w * w3;
    }
    float bb = b2f[f];

    float sum = 0.0f;
    int curg = -1;
    for (int j = 0; j < 4; j++) {
        int i = i0 + half + 2 * j;
        if (i >= N) continue;
        float val = fmaxf(acc[j] + bb, 0.0f);
        int g = batch[i];
        if (g != curg) {
            if (curg >= 0) atomicAdd(&pooled[curg * H + f], sum);
            curg = g;
            sum = 0.0f;
        }
        sum += val;
    }
    if (curg >= 0) atomicAdd(&pooled[curg * H + f], sum);
}

// out[g] = (pooled[g]/max(cnt,1)) @ Wl + bl  -> detected dtype
static __global__ void gcn364_final(const float* __restrict__ pooled,
                                    const float* __restrict__ cnt,
                                    const float* __restrict__ wlf,
                                    const float* __restrict__ blf,
                                    const int* __restrict__ flag,
                                    void* __restrict__ out, int G) {
    int g = blockIdx.x;
    int o = threadIdx.x;
    if (g >= G || o >= OUTF) return;
    float inv = 1.0f / fmaxf(cnt[g], 1.0f);
    float acc = 0.0f;
    for (int k = 0; k < H; k++)
        acc += pooled[g * H + k] * wlf[k * OUTF + o];
    float v = acc * inv + blf[o];
    if (*flag) ((float*)out)[g * OUTF + o] = v;
    else       ((unsigned short*)out)[g * OUTF + o] = gcn364_f2bf(v);
}

extern "C" void kernel_launch(void* const* d_in, const int* in_sizes, int n_in,
                              void* d_out, int out_size, void* d_ws, size_t ws_size,
                              hipStream_t stream) {
    const void* x  = d_in[0];
    const int* edge_index = (const int*)d_in[1];
    const int* batch      = (const int*)d_in[2];
    const void* W1 = d_in[3];
    const void* b1 = d_in[4];
    const void* W2 = d_in[5];
    const void* b2 = d_in[6];
    const void* Wl = d_in[7];
    const void* bl = d_in[8];

    const int N = in_sizes[0] / DIN;
    const int E = in_sizes[1] / 2;
    const int G = out_size / OUTF;
    const int* src = edge_index;
    const int* dst = edge_index + E;
    const int NB = (N + 1023) / 1024;   // scan blocks (must be <= 256)

    // ---- workspace layout (4B units) ----
    char* wsb = (char*)d_ws;
    int*   deg      = (int*)wsb;                                  // N      (zeroed)
    float* pooled   = (float*)(deg + N);                          // G*H    (zeroed)
    int*   off      = (int*)(pooled + (size_t)G * H);             // N
    int*   partials = off + N;                                    // 256
    float* cnt      = (float*)(partials + 256);                   // G
    float* aggX     = cnt + G;                                    // 3N
    float* dinvs    = aggX + (size_t)DIN * N;                     // N
    float* xf       = dinvs + N;                                  // 3N
    float* wf       = xf + (size_t)DIN * N;                       // NWEIGHT
    int*   flag     = (int*)(wf + NWEIGHT);                       // 1
    int*   esrc     = flag + 1;                                   // E
    unsigned short* h1s = (unsigned short*)(esrc + E);            // N*H ushorts

    float* w1f = wf;
    float* b1f = w1f + 384;
    float* w2f = b1f + 128;
    float* b2f = w2f + 16384;
    float* wlf = b2f + 128;
    float* blf = wlf + 1280;

    // zero only deg + pooled (contiguous at ws start)
    hipMemsetAsync(d_ws, 0, ((size_t)N + (size_t)G * H) * 4, stream);

    gcn364_detect<<<1, 256, 0, stream>>>((const unsigned short*)x, flag);
    {
        int total = DIN * N + NWEIGHT;
        gcn364_convert<<<(total + 255) / 256, 256, 0, stream>>>(
            x, W1, b1, W2, b2, Wl, bl, flag, xf, N);
    }
    gcn364_deg<<<(E + 255) / 256, 256, 0, stream>>>(dst, deg, E);
    gcn364_cnt<<<(G + 63) / 64, 64, 0, stream>>>(batch, cnt, N, G);
    gcn364_scan1<<<NB, 256, 0, stream>>>(deg, off, partials, N);
    gcn364_scan2<<<1, 256, 0, stream>>>(partials, NB);
    gcn364_scan3<<<(N + 255) / 256, 256, 0, stream>>>(off, partials, deg, dinvs, xf, N);
    gcn364_fill<<<(E + 255) / 256, 256, 0, stream>>>(src, dst, off, esrc, E);
    gcn364_agg1<<<(N + 255) / 256, 256, 0, stream>>>(esrc, off, xf, dinvs, aggX, N);
    gcn364_layer1<<<((size_t)N * H + 255) / 256, 256, 0, stream>>>(
        xf, aggX, dinvs, w1f, b1f, h1s, N);
    gcn364_agg2pool<<<(N + MPB - 1) / MPB, 256, 0, stream>>>(
        esrc, off, (const unsigned int*)h1s, dinvs, w2f, b2f, batch, pooled, N);
    gcn364_final<<<G, 64, 0, stream>>>(pooled, cnt, wlf, blf, flag, d_out, G);
}

// Round 5
// 463.645 us; speedup vs baseline: 5.1346x; 1.1012x over previous
//
#include <hip/hip_runtime.h>

// GCN: 2x GCNConv(+self-loop sym-norm) + ReLU, global mean pool, linear head.
// N=100000, E=1600000, G=100, D_IN=3, H=128, OUT=10.
//
// R4->R5: (1) agg2pool quad-edge gather: dwordx4/lane, 16 lanes/row, 4 edges
// per wave-iter -> ~5.3 wave-instrs/edge vs ~8.5; MPB 8->16. (2) agg1+layer1
// fused: 16 lanes/node parallel gather + shfl_xor reduce + coalesced 16B
// packed-bf16 stores. (3) deg merged into convert, cnt into scan2.
//
// All kernels static + gcn364_ prefix (cross-.so symbol collisions caused the
// round-1 silent failure). Runtime dtype probe handles bf16/fp32 harness mode.

#define DIN 3
#define H 128
#define OUTF 10
#define NWEIGHT (384 + 128 + 16384 + 128 + 1280 + 10)  // W1,b1,W2,b2,Wl,bl

__device__ __forceinline__ float gcn364_bf2f(unsigned short u) {
    return __uint_as_float(((unsigned int)u) << 16);
}
__device__ __forceinline__ float gcn364_lo(unsigned int u) {
    return __uint_as_float(u << 16);
}
__device__ __forceinline__ float gcn364_hi(unsigned int u) {
    return __uint_as_float(u & 0xffff0000u);
}
__device__ __forceinline__ unsigned short gcn364_f2bf(float f) {
    unsigned int u = __float_as_uint(f);
    u += 0x7FFFu + ((u >> 16) & 1u);   // round-to-nearest-even
    return (unsigned short)(u >> 16);
}

// ---- dtype probe: flag=1 if x is fp32, flag=0 if bf16 ----
static __global__ void gcn364_detect(const unsigned short* __restrict__ xraw,
                                     int* __restrict__ flag) {
    __shared__ int cnt;
    if (threadIdx.x == 0) cnt = 0;
    __syncthreads();
    unsigned short u = xraw[threadIdx.x];
    int e = (u >> 7) & 0xFF;
    int outlier = (e < 100 || e > 140) ? 1 : 0;
    atomicAdd(&cnt, outlier);
    __syncthreads();
    if (threadIdx.x == 0) *flag = (cnt > 32) ? 1 : 0;
}

// ---- convert float inputs to fp32 region + int degree count (merged) ----
static __global__ void gcn364_convdeg(const void* __restrict__ x,
                                      const void* __restrict__ W1, const void* __restrict__ b1,
                                      const void* __restrict__ W2, const void* __restrict__ b2,
                                      const void* __restrict__ Wl, const void* __restrict__ bl,
                                      const int* __restrict__ flag,
                                      float* __restrict__ dstf,
                                      const int* __restrict__ edst, int* __restrict__ deg,
                                      int N, int E) {
    int i = blockIdx.x * blockDim.x + threadIdx.x;
    if (i < E) atomicAdd(&deg[edst[i]], 1);
    int total = DIN * N + NWEIGHT;
    if (i >= total) return;
    const void* srcp; int j = i;
    if (j < DIN * N) { srcp = x; }
    else {
        j -= DIN * N;
        if      (j < 384)                       { srcp = W1; }
        else if ((j -= 384)   < 128)            { srcp = b1; }
        else if ((j -= 128)   < 16384)          { srcp = W2; }
        else if ((j -= 16384) < 128)            { srcp = b2; }
        else if ((j -= 128)   < 1280)           { srcp = Wl; }
        else    { j -= 1280;                      srcp = bl; }
    }
    float v = (*flag) ? ((const float*)srcp)[j]
                      : gcn364_bf2f(((const unsigned short*)srcp)[j]);
    dstf[i] = v;
}

// ---- exclusive scan of deg[N] -> off[N], 1024 items/block ----
static __global__ void gcn364_scan1(const int* __restrict__ deg, int* __restrict__ off,
                                    int* __restrict__ partials, int N) {
    __shared__ int sh[256];
    int t = threadIdx.x;
    int base = blockIdx.x * 1024 + t * 4;
    int v0 = (base + 0 < N) ? deg[base + 0] : 0;
    int v1 = (base + 1 < N) ? deg[base + 1] : 0;
    int v2 = (base + 2 < N) ? deg[base + 2] : 0;
    int v3 = (base + 3 < N) ? deg[base + 3] : 0;
    int s = v0 + v1 + v2 + v3;
    sh[t] = s;
    __syncthreads();
    for (int d = 1; d < 256; d <<= 1) {
        int val = (t >= d) ? sh[t - d] : 0;
        __syncthreads();
        sh[t] += val;
        __syncthreads();
    }
    int excl = sh[t] - s;
    int run = excl;
    if (base + 0 < N) off[base + 0] = run; run += v0;
    if (base + 1 < N) off[base + 1] = run; run += v1;
    if (base + 2 < N) off[base + 2] = run; run += v2;
    if (base + 3 < N) off[base + 3] = run;
    if (t == 255) partials[blockIdx.x] = sh[255];
}

// block 0: scan of partials; block 1: nodes-per-graph via binary search
static __global__ void gcn364_scan2cnt(int* __restrict__ partials, int nb,
                                       const int* __restrict__ batch,
                                       float* __restrict__ cnt, int N, int G) {
    if (blockIdx.x == 0) {
        __shared__ int sh[256];
        int t = threadIdx.x;
        int v = (t < nb) ? partials[t] : 0;
        sh[t] = v;
        __syncthreads();
        for (int d = 1; d < 256; d <<= 1) {
            int val = (t >= d) ? sh[t - d] : 0;
            __syncthreads();
            sh[t] += val;
            __syncthreads();
        }
        if (t < nb) partials[t] = sh[t] - v;   // exclusive
    } else {
        for (int g = threadIdx.x; g < G; g += blockDim.x) {
            int lo = 0, hi = N;
            while (lo < hi) { int m = (lo + hi) >> 1; if (batch[m] < g) lo = m + 1; else hi = m; }
            int a = lo;
            lo = 0; hi = N;
            while (lo < hi) { int m = (lo + hi) >> 1; if (batch[m] < g + 1) lo = m + 1; else hi = m; }
            cnt[g] = (float)(lo - a);
        }
    }
}

// scan finalize + dinvs + in-place pre-scale of xf by dinvs
static __global__ void gcn364_scan3(int* __restrict__ off, const int* __restrict__ partials,
                                    const int* __restrict__ deg, float* __restrict__ dinvs,
                                    float* __restrict__ xf, int N) {
    int i = blockIdx.x * blockDim.x + threadIdx.x;
    if (i >= N) return;
    off[i] += partials[i >> 10];
    float di = rsqrtf((float)deg[i] + 1.0f);
    dinvs[i] = di;
    xf[i * DIN + 0] *= di;
    xf[i * DIN + 1] *= di;
    xf[i * DIN + 2] *= di;
}

// bucket fill: off[] doubles as cursor; afterwards off[i] == end offset of node i
static __global__ void gcn364_fill(const int* __restrict__ src, const int* __restrict__ dst,
                                   int* __restrict__ off, int* __restrict__ esrc, int E) {
    int e = blockIdx.x * blockDim.x + threadIdx.x;
    if (e >= E) return;
    int p = atomicAdd(&off[dst[e]], 1);
    esrc[p] = src[e];
}

// Fused layer-1 agg + GEMM + relu: 16 lanes per node, 4 nodes per wave.
// Lanes stripe the node's edge list (parallel scattered xf gather), shfl_xor
// reduce 3 sums, then each lane computes 8 features -> one 16B packed store.
// xf pre-scaled by dinvs; h1s = dinvs*relu(...) (pre-scaled for layer 2).
static __global__ void gcn364_l1fused(const int* __restrict__ esrc,
                                      const int* __restrict__ endoff,
                                      const float* __restrict__ xf,
                                      const float* __restrict__ dinvs,
                                      const float* __restrict__ w1f,
                                      const float* __restrict__ b1f,
                                      unsigned short* __restrict__ h1s, int N) {
    int lane = threadIdx.x & 63;
    int wv = threadIdx.x >> 6;
    int grp = lane >> 4;
    int sub = lane & 15;
    int i = (blockIdx.x * 4 + wv) * 4 + grp;

    float a0 = 0.f, a1 = 0.f, a2 = 0.f;
    if (i < N) {
        int p0 = (i == 0) ? 0 : endoff[i - 1];
        int p1 = endoff[i];
        for (int p = p0 + sub; p < p1; p += 16) {
            int s = esrc[p];
            a0 += xf[s * DIN + 0];
            a1 += xf[s * DIN + 1];
            a2 += xf[s * DIN + 2];
        }
    }
    // reduce within the 16-lane group
    for (int d = 1; d < 16; d <<= 1) {
        a0 += __shfl_xor(a0, d);
        a1 += __shfl_xor(a1, d);
        a2 += __shfl_xor(a2, d);
    }
    if (i >= N) return;
    float di = dinvs[i];
    float v0 = di * (a0 + xf[i * DIN + 0]);
    float v1 = di * (a1 + xf[i * DIN + 1]);
    float v2 = di * (a2 + xf[i * DIN + 2]);

    unsigned int outp[4];
    #pragma unroll
    for (int q = 0; q < 4; q++) {
        int f = sub * 8 + q * 2;
        float r0 = di * fmaxf(v0 * w1f[f]     + v1 * w1f[H + f]     + v2 * w1f[2 * H + f]     + b1f[f],     0.f);
        float r1 = di * fmaxf(v0 * w1f[f + 1] + v1 * w1f[H + f + 1] + v2 * w1f[2 * H + f + 1] + b1f[f + 1], 0.f);
        outp[q] = (unsigned int)gcn364_f2bf(r0) | ((unsigned int)gcn364_f2bf(r1) << 16);
    }
    uint4 o; o.x = outp[0]; o.y = outp[1]; o.z = outp[2]; o.w = outp[3];
    *(uint4*)(h1s + (size_t)i * H + sub * 8) = o;
}

// Fused layer-2 CSR aggregation + GEMM + relu + mean-pool.
// Block = 256 thr = 4 waves; MPB=16 nodes/block (4 per wave).
// Phase A: quad-edge gather — lane loads uint4 (16B), 16 lanes cover a row,
// 4 edges per iteration (bpermute-broadcast indices). Tail edges + self-loop
// in 16-lane scalar mode. Phase B: 8-acc GEMM, float4 LDS reads, grouped
// atomics into pooled (batch sorted).
#define MPB 16
static __global__ void gcn364_agg2pool(const int* __restrict__ esrc,
                                       const int* __restrict__ endoff,
                                       const uint4* __restrict__ h1u4,
                                       const float* __restrict__ dinvs,
                                       const float* __restrict__ w2f,
                                       const float* __restrict__ b2f,
                                       const int* __restrict__ batch,
                                       float* __restrict__ pooled, int N) {
    __shared__ float vsh[MPB][H];
    int i0 = blockIdx.x * MPB;
    int wave = threadIdx.x >> 6;
    int lane = threadIdx.x & 63;
    int grp = lane >> 4;
    int sub = lane & 15;

    for (int r = 0; r < 4; r++) {
        int node = wave * 4 + r;
        int i = i0 + node;
        float acc[8] = {0.f, 0.f, 0.f, 0.f, 0.f, 0.f, 0.f, 0.f};
        float di = 0.f;
        if (i < N) {
            int p0 = (i == 0) ? 0 : endoff[i - 1];
            int p1 = endoff[i];
            int pc = p0;
            while (p1 - pc >= 4) {
                int cc = p1 - pc;
                if (cc > 64) cc = 64;
                int ncc = cc & ~3;
                int ev = (lane < ncc) ? esrc[pc + lane] : 0;
                #pragma unroll 4
                for (int j = 0; j < (ncc >> 2); j++) {
                    int s = __shfl(ev, (j << 2) + grp);
                    uint4 hv = h1u4[(size_t)s * (H / 8) + sub];
                    acc[0] += gcn364_lo(hv.x); acc[1] += gcn364_hi(hv.x);
                    acc[2] += gcn364_lo(hv.y); acc[3] += gcn364_hi(hv.y);
                    acc[4] += gcn364_lo(hv.z); acc[5] += gcn364_hi(hv.z);
                    acc[6] += gcn364_lo(hv.w); acc[7] += gcn364_hi(hv.w);
                }
                pc += ncc;
            }
            // tail edges (0..3) + self-loop, 16-lane mode
            for (int t = pc; t <= p1; t++) {         // t==p1 -> self-loop
                int s = (t == p1) ? i : esrc[t];
                if (grp == 0) {
                    uint4 hv = h1u4[(size_t)s * (H / 8) + sub];
                    acc[0] += gcn364_lo(hv.x); acc[1] += gcn364_hi(hv.x);
                    acc[2] += gcn364_lo(hv.y); acc[3] += gcn364_hi(hv.y);
                    acc[4] += gcn364_lo(hv.z); acc[5] += gcn364_hi(hv.z);
                    acc[6] += gcn364_lo(hv.w); acc[7] += gcn364_hi(hv.w);
                }
            }
            di = dinvs[i];
        }
        // combine the 4 lane-groups -> lanes 0..15
        #pragma unroll
        for (int k = 0; k < 8; k++) {
            acc[k] += __shfl_down(acc[k], 32);
            acc[k] += __shfl_down(acc[k], 16);
        }
        if (lane < 16) {
            float4 w0 = make_float4(acc[0] * di, acc[1] * di, acc[2] * di, acc[3] * di);
            float4 w1 = make_float4(acc[4] * di, acc[5] * di, acc[6] * di, acc[7] * di);
            *(float4*)&vsh[node][sub * 8 + 0] = w0;
            *(float4*)&vsh[node][sub * 8 + 4] = w1;
        }
    }
    __syncthreads();

    int f = threadIdx.x & (H - 1);
    int half = threadIdx.x >> 7;
    float acc2[8] = {0.f, 0.f, 0.f, 0.f, 0.f, 0.f, 0.f, 0.f};
    for (int k4 = 0; k4 < H / 4; k4++) {
        float w0 = w2f[(k4 * 4 + 0) * H + f];
        float w1 = w2f[(k4 * 4 + 1) * H + f];
        float w2 = w2f[(k4 * 4 + 2) * H + f];
        float w3 = w2f[(k4 * 4 + 3) * H + f];
        #pragma unroll
        for (int n = 0; n < 8; n++) {
            float4 v = *(const float4*)&vsh[2 * n + half][k4 * 4];
            acc2[n] += v.x * w0 + v.y * w1 + v.z * w2 + v.w * w3;
        }
    }
    float bb = b2f[f];

    float sum = 0.0f;
    int curg = -1;
    #pragma unroll
    for (int j = 0; j < 8; j++) {
        int i = i0 + half + 2 * j;
        if (i >= N) continue;
        float val = fmaxf(acc2[j] + bb, 0.0f);
        int g = batch[i];
        if (g != curg) {
            if (curg >= 0) atomicAdd(&pooled[curg * H + f], sum);
            curg = g;
            sum = 0.0f;
        }
        sum += val;
    }
    if (curg >= 0) atomicAdd(&pooled[curg * H + f], sum);
}

// out[g] = (pooled[g]/max(cnt,1)) @ Wl + bl  -> detected dtype
static __global__ void gcn364_final(const float* __restrict__ pooled,
                                    const float* __restrict__ cnt,
                                    const float* __restrict__ wlf,
                                    const float* __restrict__ blf,
                                    const int* __restrict__ flag,
                                    void* __restrict__ out, int G) {
    int g = blockIdx.x;
    int o = threadIdx.x;
    if (g >= G || o >= OUTF) return;
    float inv = 1.0f / fmaxf(cnt[g], 1.0f);
    float acc = 0.0f;
    for (int k = 0; k < H; k++)
        acc += pooled[g * H + k] * wlf[k * OUTF + o];
    float v = acc * inv + blf[o];
    if (*flag) ((float*)out)[g * OUTF + o] = v;
    else       ((unsigned short*)out)[g * OUTF + o] = gcn364_f2bf(v);
}

extern "C" void kernel_launch(void* const* d_in, const int* in_sizes, int n_in,
                              void* d_out, int out_size, void* d_ws, size_t ws_size,
                              hipStream_t stream) {
    const void* x  = d_in[0];
    const int* edge_index = (const int*)d_in[1];
    const int* batch      = (const int*)d_in[2];
    const void* W1 = d_in[3];
    const void* b1 = d_in[4];
    const void* W2 = d_in[5];
    const void* b2 = d_in[6];
    const void* Wl = d_in[7];
    const void* bl = d_in[8];

    const int N = in_sizes[0] / DIN;
    const int E = in_sizes[1] / 2;
    const int G = out_size / OUTF;
    const int* src = edge_index;
    const int* dst = edge_index + E;
    const int NB = (N + 1023) / 1024;   // scan blocks (must be <= 256)

    // ---- workspace layout (4B units) ----
    char* wsb = (char*)d_ws;
    int*   deg      = (int*)wsb;                                  // N      (zeroed)
    float* pooled   = (float*)(deg + N);                          // G*H    (zeroed)
    int*   off      = (int*)(pooled + (size_t)G * H);             // N
    int*   partials = off + N;                                    // 256
    float* cnt      = (float*)(partials + 256);                   // G
    float* dinvs    = cnt + G;                                    // N
    float* xf       = dinvs + N;                                  // 3N
    float* wf       = xf + (size_t)DIN * N;                       // NWEIGHT
    int*   flag     = (int*)(wf + NWEIGHT);                       // 1
    int*   esrc     = flag + 1;                                   // E
    // align h1s to 16B for uint4 stores/loads
    size_t h1off = (((size_t)(esrc + E) - (size_t)wsb) + 15) & ~(size_t)15;
    unsigned short* h1s = (unsigned short*)(wsb + h1off);         // N*H ushorts

    float* w1f = wf;
    float* b1f = w1f + 384;
    float* w2f = b1f + 128;
    float* b2f = w2f + 16384;
    float* wlf = b2f + 128;
    float* blf = wlf + 1280;

    // zero only deg + pooled (contiguous at ws start)
    hipMemsetAsync(d_ws, 0, ((size_t)N + (size_t)G * H) * 4, stream);

    gcn364_detect<<<1, 256, 0, stream>>>((const unsigned short*)x, flag);
    {
        int total = DIN * N + NWEIGHT;
        int gmax = (E > total) ? E : total;
        gcn364_convdeg<<<(gmax + 255) / 256, 256, 0, stream>>>(
            x, W1, b1, W2, b2, Wl, bl, flag, xf, dst, deg, N, E);
    }
    gcn364_scan1<<<NB, 256, 0, stream>>>(deg, off, partials, N);
    gcn364_scan2cnt<<<2, 256, 0, stream>>>(partials, NB, batch, cnt, N, G);
    gcn364_scan3<<<(N + 255) / 256, 256, 0, stream>>>(off, partials, deg, dinvs, xf, N);
    gcn364_fill<<<(E + 255) / 256, 256, 0, stream>>>(src, dst, off, esrc, E);
    gcn364_l1fused<<<(N + 15) / 16, 256, 0, stream>>>(esrc, off, xf, dinvs, w1f, b1f, h1s, N);
    gcn364_agg2pool<<<(N + MPB - 1) / MPB, 256, 0, stream>>>(
        esrc, off, (const uint4*)h1s, dinvs, w2f, b2f, batch, pooled, N);
    gcn364_final<<<G, 64, 0, stream>>>(pooled, cnt, wlf, blf, flag, d_out, G);
}